// Round 1
// baseline (462.738 us; speedup 1.0000x reference)
//
#include <hip/hip_runtime.h>

typedef unsigned short u16;
typedef unsigned int u32;
typedef __attribute__((ext_vector_type(8))) short short8;
typedef __attribute__((ext_vector_type(4))) float f32x4;

typedef __attribute__((address_space(3))) void* lds_vp;
typedef const __attribute__((address_space(1))) void* gbl_vp;

#define GLOAD_LDS16(gsrc, ldst) \
  __builtin_amdgcn_global_load_lds((gbl_vp)(gsrc), (lds_vp)(ldst), 16, 0, 0)

#define MFMA_BF16(A, B, C) __builtin_amdgcn_mfma_f32_16x16x32_bf16((A), (B), (C), 0, 0, 0)

__device__ __forceinline__ u16 f2b(float f) {
  u32 u = __builtin_bit_cast(u32, f);
  u += 0x7fffu + ((u >> 16) & 1u);
  return (u16)(u >> 16);
}
__device__ __forceinline__ float b2f(u16 v) {
  return __builtin_bit_cast(float, ((u32)v) << 16);
}

// ---------------- fp32 -> bf16 conversion (vectorized, G13) ----------------
__global__ void cvt_f32_bf16(const float* __restrict__ in, u16* __restrict__ out, int n4) {
  int i = blockIdx.x * 256 + threadIdx.x;
  if (i >= n4) return;
  float4 v = ((const float4*)in)[i];
  ushort4 o;
  o.x = f2b(v.x); o.y = f2b(v.y); o.z = f2b(v.z); o.w = f2b(v.w);
  ((ushort4*)out)[i] = o;
}

// ---------------- RoPE cos/sin table: [2048 pos][32 pairs] ----------------
__global__ void rope_table(float2* __restrict__ tab) {
  int t = blockIdx.x * 256 + threadIdx.x;      // 65536 threads exactly
  int p = t >> 5, dp = t & 31;
  float inv = (float)pow(10000.0, -(double)dp / 32.0);  // matches jax fp32 inv_freq
  float ang = (float)p * inv;
  tab[t] = make_float2(cosf(ang), sinf(ang));
}

// ---------------- RoPE apply in-place on Q (scaled 0.125) and K ----------------
__global__ void rope_apply(u16* __restrict__ Qd, u16* __restrict__ Kd,
                           const float2* __restrict__ tab, const int* __restrict__ pos) {
  int t = blockIdx.x * 256 + threadIdx.x;      // B*H*S*32 = 4194304 exactly
  int dp = t & 31;
  int s  = (t >> 5) & 2047;
  int bh = t >> 16;
  int p = pos[s];
  float2 cs = tab[(p << 5) + dp];
  size_t base = ((size_t)(bh * 2048 + s)) * 64 + 2 * dp;
  u32 uq = *(const u32*)&Qd[base];
  float x1 = b2f((u16)(uq & 0xffff)), x2 = b2f((u16)(uq >> 16));
  float r1 = (x1 * cs.x - x2 * cs.y) * 0.125f;
  float r2 = (x1 * cs.y + x2 * cs.x) * 0.125f;
  *(u32*)&Qd[base] = (u32)f2b(r1) | ((u32)f2b(r2) << 16);
  u32 uk = *(const u32*)&Kd[base];
  x1 = b2f((u16)(uk & 0xffff)); x2 = b2f((u16)(uk >> 16));
  r1 = x1 * cs.x - x2 * cs.y;
  r2 = x1 * cs.y + x2 * cs.x;
  *(u32*)&Kd[base] = (u32)f2b(r1) | ((u32)f2b(r2) << 16);
}

// ---------------- GEMM C = A @ Bt^T, A[M][K] bf16, Bt[N][K] bf16 ----------------
// m97 structure: 128x128 tile, BK=32, 4 waves (2x2), 16x16x32 MFMA, global_load_lds w16.
// EPI==1: scatter qkv -> Q/K [B][H][S][64], V transposed [B][H][64][S]
// EPI==2: fp32 row-major C
template<int EPI>
__global__ __launch_bounds__(256, 2) void gemm_bt(
    const u16* __restrict__ A, const u16* __restrict__ Bt,
    float* __restrict__ Cf, int M, int N, int K,
    u16* __restrict__ qp, u16* __restrict__ kp, u16* __restrict__ vp)
{
  __shared__ u16 As[128 * 32];
  __shared__ u16 Bs[128 * 32];
  const int t = threadIdx.x;
  const int l = t & 63, w = t >> 6;
  const int wr = w >> 1, wc = w & 1;
  const int tm = blockIdx.x * 128, tn = blockIdx.y * 128;
  const int srow = w * 16 + (l >> 2);
  const int scol = (l & 3) * 8;
  const u16* aS = A + (size_t)(tm + srow) * K + scol;
  const u16* bS = Bt + (size_t)(tn + srow) * K + scol;
  f32x4 acc[4][4] = {};
  for (int kt = 0; kt < K; kt += 32) {
    __syncthreads();
    GLOAD_LDS16(aS + kt,              &As[(w * 16) * 32]);
    GLOAD_LDS16(aS + 64 * (size_t)K + kt, &As[(64 + w * 16) * 32]);
    GLOAD_LDS16(bS + kt,              &Bs[(w * 16) * 32]);
    GLOAD_LDS16(bS + 64 * (size_t)K + kt, &Bs[(64 + w * 16) * 32]);
    asm volatile("s_waitcnt vmcnt(0)" ::: "memory");
    __syncthreads();
    short8 af[4], bf[4];
    #pragma unroll
    for (int m = 0; m < 4; ++m)
      af[m] = *(const short8*)&As[(wr * 64 + m * 16 + (l & 15)) * 32 + (l >> 4) * 8];
    #pragma unroll
    for (int n = 0; n < 4; ++n)
      bf[n] = *(const short8*)&Bs[(wc * 64 + n * 16 + (l & 15)) * 32 + (l >> 4) * 8];
    #pragma unroll
    for (int m = 0; m < 4; ++m)
      #pragma unroll
      for (int n = 0; n < 4; ++n)
        acc[m][n] = MFMA_BF16(af[m], bf[n], acc[m][n]);
  }
  const int rl = (l >> 4) * 4;
  const int cl = l & 15;
  if constexpr (EPI == 2) {
    #pragma unroll
    for (int m = 0; m < 4; ++m)
      #pragma unroll
      for (int n = 0; n < 4; ++n) {
        int col = tn + wc * 64 + n * 16 + cl;
        #pragma unroll
        for (int r = 0; r < 4; ++r) {
          int row = tm + wr * 64 + m * 16 + rl + r;
          Cf[(size_t)row * N + col] = acc[m][n][r];
        }
      }
  } else {  // EPI == 1
    #pragma unroll
    for (int m = 0; m < 4; ++m)
      #pragma unroll
      for (int n = 0; n < 4; ++n) {
        int j0 = tn + wc * 64 + n * 16;          // 16-aligned, uniform head/which per frag
        int which = j0 >> 10;
        int h = (j0 & 1023) >> 6;
        int d = (j0 & 63) + cl;
        u16* dst = which == 0 ? qp : (which == 1 ? kp : vp);
        #pragma unroll
        for (int r = 0; r < 4; ++r) {
          int i = tm + wr * 64 + m * 16 + rl + r;
          int b = i >> 11, s = i & 2047;
          u16 bv = f2b(acc[m][n][r]);
          if (which < 2)
            dst[(size_t)((b * 16 + h) * 2048 + s) * 64 + d] = bv;       // [B][H][S][64]
          else
            dst[(size_t)((b * 16 + h) * 64 + d) * 2048 + s] = bv;       // V^T: [B][H][64][S]
        }
      }
  }
}

// ---------------- causal flash attention ----------------
// grid (S/64, B*H); 4 waves; wave = 16 q-rows; KV step 32.
// Q [B][H][S][64] (rope'd, pre-scaled), K [B][H][S][64] (rope'd), Vt [B][H][64][S].
// Out: Ob [B][S][H*64] bf16.
__global__ __launch_bounds__(256, 2) void attn_fwd(
    const u16* __restrict__ Q, const u16* __restrict__ Kg,
    const u16* __restrict__ Vt, u16* __restrict__ Ob)
{
  __shared__ u16 Ks[32 * 64];       // [key][d]
  __shared__ u16 Vs[64 * 32];       // [d][key]  (from pre-transposed V)
  __shared__ u16 Ps[4][16 * 32];    // per-wave P tile [q][key]
  const int t = threadIdx.x;
  const int l = t & 63, w = t >> 6;
  const int bh = blockIdx.y;
  const int b = bh >> 4, h = bh & 15;
  const int qb = blockIdx.x * 64;
  const int qw = qb + w * 16;
  const int rl = (l >> 4) * 4, cl = l & 15, koff = (l >> 4) * 8;
  const u16* Qrow = Q + (size_t)(bh * 2048 + qw + cl) * 64;
  short8 qf0 = *(const short8*)&Qrow[koff];
  short8 qf1 = *(const short8*)&Qrow[32 + koff];
  const u16* Kb = Kg + (size_t)bh * 2048 * 64;
  const u16* Vb = Vt + (size_t)bh * 64 * 2048;
  f32x4 o0 = {}, o1 = {}, o2 = {}, o3 = {};
  float mrun[4] = {-1e30f, -1e30f, -1e30f, -1e30f};
  float lrun[4] = {0.f, 0.f, 0.f, 0.f};
  const int kv_end = qb + 64;
  const int ksrow = t >> 3, kscol = (t & 7) * 8;   // K tile [32][64]
  const int vsrow = t >> 2, vscol = (t & 3) * 8;   // Vt tile [64][32]
  for (int kv = 0; kv < kv_end; kv += 32) {
    __syncthreads();
    GLOAD_LDS16(Kb + (size_t)(kv + ksrow) * 64 + kscol, &Ks[w * 512]);
    GLOAD_LDS16(Vb + (size_t)vsrow * 2048 + kv + vscol, &Vs[w * 512]);
    asm volatile("s_waitcnt vmcnt(0)" ::: "memory");
    __syncthreads();
    if (kv <= qw + 15) {                 // wave-uniform: skip all-masked tiles
      f32x4 s0 = {}, s1 = {};
      {
        short8 k0 = *(const short8*)&Ks[cl * 64 + koff];
        short8 k1 = *(const short8*)&Ks[cl * 64 + 32 + koff];
        s0 = MFMA_BF16(qf0, k0, s0);
        s0 = MFMA_BF16(qf1, k1, s0);
        short8 k2 = *(const short8*)&Ks[(16 + cl) * 64 + koff];
        short8 k3 = *(const short8*)&Ks[(16 + cl) * 64 + 32 + koff];
        s1 = MFMA_BF16(qf0, k2, s1);
        s1 = MFMA_BF16(qf1, k3, s1);
      }
      if (kv + 31 > qw) {                // tile touches the diagonal
        #pragma unroll
        for (int r = 0; r < 4; ++r) {
          int q = qw + rl + r;
          if (kv + cl > q)      s0[r] = -1e30f;
          if (kv + 16 + cl > q) s1[r] = -1e30f;
        }
      }
      #pragma unroll
      for (int r = 0; r < 4; ++r) {
        float tmax = fmaxf(s0[r], s1[r]);
        #pragma unroll
        for (int off = 8; off; off >>= 1) tmax = fmaxf(tmax, __shfl_xor(tmax, off));
        float mnew = fmaxf(mrun[r], tmax);
        float alpha = __expf(mrun[r] - mnew);
        float p0 = __expf(s0[r] - mnew);
        float p1 = __expf(s1[r] - mnew);
        float ts = p0 + p1;
        #pragma unroll
        for (int off = 8; off; off >>= 1) ts += __shfl_xor(ts, off);
        lrun[r] = lrun[r] * alpha + ts;
        mrun[r] = mnew;
        o0[r] *= alpha; o1[r] *= alpha; o2[r] *= alpha; o3[r] *= alpha;
        Ps[w][(rl + r) * 32 + cl]      = f2b(p0);
        Ps[w][(rl + r) * 32 + 16 + cl] = f2b(p1);
      }
      // fence: cross-lane LDS RAW within the wave (outside C memory model)
      asm volatile("s_waitcnt lgkmcnt(0)" ::: "memory");
      short8 pa = *(const short8*)&Ps[w][cl * 32 + koff];
      short8 v0 = *(const short8*)&Vs[(0  + cl) * 32 + koff];
      o0 = MFMA_BF16(pa, v0, o0);
      short8 v1 = *(const short8*)&Vs[(16 + cl) * 32 + koff];
      o1 = MFMA_BF16(pa, v1, o1);
      short8 v2 = *(const short8*)&Vs[(32 + cl) * 32 + koff];
      o2 = MFMA_BF16(pa, v2, o2);
      short8 v3 = *(const short8*)&Vs[(48 + cl) * 32 + koff];
      o3 = MFMA_BF16(pa, v3, o3);
    }
  }
  u16* obase = Ob + (size_t)(b * 2048 + qw) * 1024 + h * 64;
  #pragma unroll
  for (int r = 0; r < 4; ++r) {
    float inv = 1.0f / lrun[r];
    int row = rl + r;
    obase[(size_t)row * 1024 + 0  + cl] = f2b(o0[r] * inv);
    obase[(size_t)row * 1024 + 16 + cl] = f2b(o1[r] * inv);
    obase[(size_t)row * 1024 + 32 + cl] = f2b(o2[r] * inv);
    obase[(size_t)row * 1024 + 48 + cl] = f2b(o3[r] * inv);
  }
}

extern "C" void kernel_launch(void* const* d_in, const int* in_sizes, int n_in,
                              void* d_out, int out_size, void* d_ws, size_t ws_size,
                              hipStream_t stream) {
  const float* x  = (const float*)d_in[0];
  const float* Wq = (const float*)d_in[1];
  const float* Wk = (const float*)d_in[2];
  const float* Wv = (const float*)d_in[3];
  const float* Wo = (const float*)d_in[4];
  const int* tok  = (const int*)d_in[5];

  char* ws = (char*)d_ws;
  // layout (bytes):                                   size
  u16*   xb   = (u16*)(ws);                        // 16 MiB  (x bf16; reused as attn-out)
  u16*   wqkv = (u16*)(ws + (16u << 20));          //  6 MiB  ([3072][1024] = Wq;Wk;Wv)
  u16*   wo   = (u16*)(ws + (22u << 20));          //  2 MiB
  u16*   qws  = (u16*)(ws + (24u << 20));          // 16 MiB  [B][H][S][64]
  u16*   kws  = (u16*)(ws + (40u << 20));          // 16 MiB  [B][H][S][64]
  u16*   vws  = (u16*)(ws + (56u << 20));          // 16 MiB  [B][H][64][S]
  float2* tab = (float2*)(ws + (72u << 20));       // 512 KiB -> total 72.5 MiB

  cvt_f32_bf16<<<8192, 256, 0, stream>>>(x, xb, 2097152);
  cvt_f32_bf16<<<1024, 256, 0, stream>>>(Wq, wqkv,               262144);
  cvt_f32_bf16<<<1024, 256, 0, stream>>>(Wk, wqkv + (1u << 20),  262144);
  cvt_f32_bf16<<<1024, 256, 0, stream>>>(Wv, wqkv + (2u << 20),  262144);
  cvt_f32_bf16<<<1024, 256, 0, stream>>>(Wo, wo,                 262144);
  rope_table<<<256, 256, 0, stream>>>(tab);

  gemm_bt<1><<<dim3(64, 24), 256, 0, stream>>>(xb, wqkv, nullptr, 8192, 3072, 1024,
                                               qws, kws, vws);
  rope_apply<<<16384, 256, 0, stream>>>(qws, kws, tab, tok);
  attn_fwd<<<dim3(32, 64), 256, 0, stream>>>(qws, kws, vws, xb /* reused as Ob */);
  gemm_bt<2><<<dim3(64, 8), 256, 0, stream>>>(xb, wo, (float*)d_out, 8192, 1024, 1024,
                                              nullptr, nullptr, nullptr);
}

// Round 2
// 340.522 us; speedup vs baseline: 1.3589x; 1.3589x over previous
//
#include <hip/hip_runtime.h>

typedef unsigned short u16;
typedef unsigned int u32;
typedef __attribute__((ext_vector_type(8))) short short8;
typedef __attribute__((ext_vector_type(4))) float f32x4;

typedef __attribute__((address_space(3))) void* lds_vp;
typedef const __attribute__((address_space(1))) void* gbl_vp;

#define GLOAD_LDS16(gsrc, ldst) \
  __builtin_amdgcn_global_load_lds((gbl_vp)(gsrc), (lds_vp)(ldst), 16, 0, 0)

#define MFMA_BF16(A, B, C) __builtin_amdgcn_mfma_f32_16x16x32_bf16((A), (B), (C), 0, 0, 0)

__device__ __forceinline__ u16 f2b(float f) {
  u32 u = __builtin_bit_cast(u32, f);
  u += 0x7fffu + ((u >> 16) & 1u);
  return (u16)(u >> 16);
}
__device__ __forceinline__ float b2f(u16 v) {
  return __builtin_bit_cast(float, ((u32)v) << 16);
}

// ---------------- fp32 -> bf16 conversion (vectorized, G13) ----------------
__global__ void cvt_f32_bf16(const float* __restrict__ in, u16* __restrict__ out, int n4) {
  int i = blockIdx.x * 256 + threadIdx.x;
  if (i >= n4) return;
  float4 v = ((const float4*)in)[i];
  ushort4 o;
  o.x = f2b(v.x); o.y = f2b(v.y); o.z = f2b(v.z); o.w = f2b(v.w);
  ((ushort4*)out)[i] = o;
}

// ---------------- RoPE cos/sin table: [2048 pos][32 pairs] ----------------
__global__ void rope_table(float2* __restrict__ tab) {
  int t = blockIdx.x * 256 + threadIdx.x;      // 65536 threads exactly
  int p = t >> 5, dp = t & 31;
  float inv = (float)pow(10000.0, -(double)dp / 32.0);
  float ang = (float)p * inv;
  tab[t] = make_float2(cosf(ang), sinf(ang));
}

// ---------------- RoPE apply in-place on Q (scaled 0.125) and K ----------------
__global__ void rope_apply(u16* __restrict__ Qd, u16* __restrict__ Kd,
                           const float2* __restrict__ tab, const int* __restrict__ pos) {
  int t = blockIdx.x * 256 + threadIdx.x;      // B*H*S*32 = 4194304 exactly
  int dp = t & 31;
  int s  = (t >> 5) & 2047;
  int bh = t >> 16;
  int p = pos[s];
  float2 cs = tab[(p << 5) + dp];
  size_t base = ((size_t)(bh * 2048 + s)) * 64 + 2 * dp;
  u32 uq = *(const u32*)&Qd[base];
  float x1 = b2f((u16)(uq & 0xffff)), x2 = b2f((u16)(uq >> 16));
  float r1 = (x1 * cs.x - x2 * cs.y) * 0.125f;
  float r2 = (x1 * cs.y + x2 * cs.x) * 0.125f;
  *(u32*)&Qd[base] = (u32)f2b(r1) | ((u32)f2b(r2) << 16);
  u32 uk = *(const u32*)&Kd[base];
  x1 = b2f((u16)(uk & 0xffff)); x2 = b2f((u16)(uk >> 16));
  r1 = x1 * cs.x - x2 * cs.y;
  r2 = x1 * cs.y + x2 * cs.x;
  *(u32*)&Kd[base] = (u32)f2b(r1) | ((u32)f2b(r2) << 16);
}

// ---------------- GEMM C = A @ Bt^T (m97 structure, unchanged this round) ----
template<int EPI>
__global__ __launch_bounds__(256, 2) void gemm_bt(
    const u16* __restrict__ A, const u16* __restrict__ Bt,
    float* __restrict__ Cf, int M, int N, int K,
    u16* __restrict__ qp, u16* __restrict__ kp, u16* __restrict__ vp)
{
  __shared__ u16 As[128 * 32];
  __shared__ u16 Bs[128 * 32];
  const int t = threadIdx.x;
  const int l = t & 63, w = t >> 6;
  const int wr = w >> 1, wc = w & 1;
  const int tm = blockIdx.x * 128, tn = blockIdx.y * 128;
  const int srow = w * 16 + (l >> 2);
  const int scol = (l & 3) * 8;
  const u16* aS = A + (size_t)(tm + srow) * K + scol;
  const u16* bS = Bt + (size_t)(tn + srow) * K + scol;
  f32x4 acc[4][4] = {};
  for (int kt = 0; kt < K; kt += 32) {
    __syncthreads();
    GLOAD_LDS16(aS + kt,              &As[(w * 16) * 32]);
    GLOAD_LDS16(aS + 64 * (size_t)K + kt, &As[(64 + w * 16) * 32]);
    GLOAD_LDS16(bS + kt,              &Bs[(w * 16) * 32]);
    GLOAD_LDS16(bS + 64 * (size_t)K + kt, &Bs[(64 + w * 16) * 32]);
    asm volatile("s_waitcnt vmcnt(0)" ::: "memory");
    __syncthreads();
    short8 af[4], bf[4];
    #pragma unroll
    for (int m = 0; m < 4; ++m)
      af[m] = *(const short8*)&As[(wr * 64 + m * 16 + (l & 15)) * 32 + (l >> 4) * 8];
    #pragma unroll
    for (int n = 0; n < 4; ++n)
      bf[n] = *(const short8*)&Bs[(wc * 64 + n * 16 + (l & 15)) * 32 + (l >> 4) * 8];
    #pragma unroll
    for (int m = 0; m < 4; ++m)
      #pragma unroll
      for (int n = 0; n < 4; ++n)
        acc[m][n] = MFMA_BF16(af[m], bf[n], acc[m][n]);
  }
  const int rl = (l >> 4) * 4;
  const int cl = l & 15;
  if constexpr (EPI == 2) {
    #pragma unroll
    for (int m = 0; m < 4; ++m)
      #pragma unroll
      for (int n = 0; n < 4; ++n) {
        int col = tn + wc * 64 + n * 16 + cl;
        #pragma unroll
        for (int r = 0; r < 4; ++r) {
          int row = tm + wr * 64 + m * 16 + rl + r;
          Cf[(size_t)row * N + col] = acc[m][n][r];
        }
      }
  } else {
    #pragma unroll
    for (int m = 0; m < 4; ++m)
      #pragma unroll
      for (int n = 0; n < 4; ++n) {
        int j0 = tn + wc * 64 + n * 16;
        int which = j0 >> 10;
        int h = (j0 & 1023) >> 6;
        int d = (j0 & 63) + cl;
        u16* dst = which == 0 ? qp : (which == 1 ? kp : vp);
        #pragma unroll
        for (int r = 0; r < 4; ++r) {
          int i = tm + wr * 64 + m * 16 + rl + r;
          int b = i >> 11, s = i & 2047;
          u16 bv = f2b(acc[m][n][r]);
          if (which < 2)
            dst[(size_t)((b * 16 + h) * 2048 + s) * 64 + d] = bv;       // [B][H][S][64]
          else
            dst[(size_t)((b * 16 + h) * 64 + d) * 2048 + s] = bv;       // V^T: [B][H][64][S]
        }
      }
  }
}

// ---------------- causal flash attention, v2 ----------------
// grid (16, B*H); 4 waves; wave = 32 q-rows (2 row-halves); KV step 64.
// K/V double-buffered in LDS with counted vmcnt + raw s_barrier (T3/T4-lite).
// All LDS tiles XOR-swizzled (T2): colblk ^= row&7; global_load_lds gets the
// inverse-swizzled SOURCE (rule 21), ds_read/ds_write apply the same XOR.
__global__ __launch_bounds__(256, 2) void attn_fwd(
    const u16* __restrict__ Q, const u16* __restrict__ Kg,
    const u16* __restrict__ Vt, u16* __restrict__ Ob)
{
  __shared__ u16 Ks[2][64 * 64];    // [key][d], swizzled
  __shared__ u16 Vs[2][64 * 64];    // [d][key], swizzled
  __shared__ u16 Ps[4][32 * 64];    // per-wave P [q][key], swizzled
  const int t = threadIdx.x;
  const int l = t & 63, w = t >> 6;
  const int bh = blockIdx.y, b = bh >> 4, h = bh & 15;
  const int qb = ((int)gridDim.x - 1 - (int)blockIdx.x) * 128;  // long blocks first
  const int qw = qb + w * 32;
  const int rl = (l >> 4) * 4, cl = l & 15, ko = l >> 4;

  short8 qf[2][2];
  {
    const u16* Qb = Q + (size_t)bh * 2048 * 64;
    #pragma unroll
    for (int hf = 0; hf < 2; ++hf) {
      const u16* qr = Qb + (size_t)(qw + hf * 16 + cl) * 64 + ko * 8;
      qf[hf][0] = *(const short8*)qr;
      qf[hf][1] = *(const short8*)(qr + 32);
    }
  }
  const u16* Kb = Kg + (size_t)bh * 2048 * 64;
  const u16* Vb = Vt + (size_t)bh * 64 * 2048;
  f32x4 o[2][4] = {};
  float mrun[2][4], lrun[2][4];
  #pragma unroll
  for (int i = 0; i < 2; ++i)
    #pragma unroll
    for (int r = 0; r < 4; ++r) { mrun[i][r] = -1e30f; lrun[i][r] = 0.f; }

  const int srow = l >> 3;        // 0..7 within 8-row segment
  const int scb  = l & 7;         // dest colblk (16B units)
  const int nt = (qb >> 6) + 2;

  auto stage = [&](int bf, int kt_) {
    const int kv_ = kt_ * 64;
    #pragma unroll
    for (int i_ = 0; i_ < 2; ++i_) {
      int r0 = w * 16 + i_ * 8;
      int row = r0 + srow;
      int gc = (scb ^ (row & 7)) * 8;           // inverse-swizzled source col (u16)
      GLOAD_LDS16(Kb + (size_t)(kv_ + row) * 64 + gc, &Ks[bf][r0 * 64]);
      GLOAD_LDS16(Vb + (size_t)row * 2048 + kv_ + gc, &Vs[bf][r0 * 64]);
    }
  };

  stage(0, 0);
  for (int kt = 0; kt < nt; ++kt) {
    const int bf = kt & 1;
    const int kv = kt * 64;
    if (kt + 1 < nt) {
      stage(bf ^ 1, kt + 1);
      asm volatile("s_waitcnt vmcnt(4)" ::: "memory");   // tile kt landed; kt+1 in flight
    } else {
      asm volatile("s_waitcnt vmcnt(0)" ::: "memory");
    }
    __builtin_amdgcn_s_barrier();
    if (kv <= qw + 31) {                 // wave-uniform causal gate (=> kv <= qw)
      // ---- QK^T: 32q x 64key ----
      f32x4 s[2][4] = {};
      #pragma unroll
      for (int kbk = 0; kbk < 4; ++kbk) {
        int row = kbk * 16 + cl, sw = row & 7;
        short8 k0 = *(const short8*)&Ks[bf][row * 64 + ((ko ^ sw) << 3)];
        short8 k1 = *(const short8*)&Ks[bf][row * 64 + (((4 + ko) ^ sw) << 3)];
        #pragma unroll
        for (int hf = 0; hf < 2; ++hf) {
          s[hf][kbk] = MFMA_BF16(qf[hf][0], k0, s[hf][kbk]);
          s[hf][kbk] = MFMA_BF16(qf[hf][1], k1, s[hf][kbk]);
        }
      }
      if (kv + 63 > qw) {                // tile touches the diagonal
        #pragma unroll
        for (int hf = 0; hf < 2; ++hf)
          #pragma unroll
          for (int kbk = 0; kbk < 4; ++kbk) {
            int key = kv + kbk * 16 + cl;
            #pragma unroll
            for (int r = 0; r < 4; ++r)
              if (key > qw + hf * 16 + rl + r) s[hf][kbk][r] = -1e30f;
          }
      }
      // ---- online softmax (one pass per 64 keys) ----
      #pragma unroll
      for (int hf = 0; hf < 2; ++hf)
        #pragma unroll
        for (int r = 0; r < 4; ++r) {
          float v0 = s[hf][0][r], v1 = s[hf][1][r];
          float v2 = s[hf][2][r], v3 = s[hf][3][r];
          float tmax = fmaxf(fmaxf(v0, v1), fmaxf(v2, v3));
          #pragma unroll
          for (int off = 8; off; off >>= 1) tmax = fmaxf(tmax, __shfl_xor(tmax, off));
          float mnew = fmaxf(mrun[hf][r], tmax);
          float al = __expf(mrun[hf][r] - mnew);
          mrun[hf][r] = mnew;
          float p0 = __expf(v0 - mnew), p1 = __expf(v1 - mnew);
          float p2 = __expf(v2 - mnew), p3 = __expf(v3 - mnew);
          float ts = (p0 + p1) + (p2 + p3);
          #pragma unroll
          for (int off = 8; off; off >>= 1) ts += __shfl_xor(ts, off);
          lrun[hf][r] = lrun[hf][r] * al + ts;
          o[hf][0][r] *= al; o[hf][1][r] *= al;
          o[hf][2][r] *= al; o[hf][3][r] *= al;
          int row = hf * 16 + rl + r;
          int base = row * 64, sw = row & 7;
          int cb = cl >> 3, ci = cl & 7;
          Ps[w][base + (((0 + cb) ^ sw) << 3) + ci] = f2b(p0);
          Ps[w][base + (((2 + cb) ^ sw) << 3) + ci] = f2b(p1);
          Ps[w][base + (((4 + cb) ^ sw) << 3) + ci] = f2b(p2);
          Ps[w][base + (((6 + cb) ^ sw) << 3) + ci] = f2b(p3);
        }
      // cross-lane LDS RAW fence (outside C memory model) + rule-18 sched fence
      asm volatile("s_waitcnt lgkmcnt(0)" ::: "memory");
      __builtin_amdgcn_sched_barrier(0);
      // ---- PV: 32q x 64d ----
      short8 pa[2][2];
      #pragma unroll
      for (int hf = 0; hf < 2; ++hf) {
        int row = hf * 16 + cl, sw = row & 7;
        pa[hf][0] = *(const short8*)&Ps[w][row * 64 + ((ko ^ sw) << 3)];
        pa[hf][1] = *(const short8*)&Ps[w][row * 64 + (((4 + ko) ^ sw) << 3)];
      }
      #pragma unroll
      for (int db = 0; db < 4; ++db) {
        int row = db * 16 + cl, sw = row & 7;
        short8 vf0 = *(const short8*)&Vs[bf][row * 64 + ((ko ^ sw) << 3)];
        short8 vf1 = *(const short8*)&Vs[bf][row * 64 + (((4 + ko) ^ sw) << 3)];
        #pragma unroll
        for (int hf = 0; hf < 2; ++hf) {
          o[hf][db] = MFMA_BF16(pa[hf][0], vf0, o[hf][db]);
          o[hf][db] = MFMA_BF16(pa[hf][1], vf1, o[hf][db]);
        }
      }
    }
    asm volatile("" ::: "memory");       // keep LDS reads on this side of the barrier
    __builtin_amdgcn_s_barrier();        // reads done before next stage overwrites
  }
  // ---- epilogue ----
  u16* ob = Ob + (size_t)(b * 2048 + qw) * 1024 + h * 64 + cl;
  #pragma unroll
  for (int hf = 0; hf < 2; ++hf)
    #pragma unroll
    for (int r = 0; r < 4; ++r) {
      float inv = 1.0f / lrun[hf][r];
      size_t ro = (size_t)(hf * 16 + rl + r) * 1024;
      ob[ro +  0] = f2b(o[hf][0][r] * inv);
      ob[ro + 16] = f2b(o[hf][1][r] * inv);
      ob[ro + 32] = f2b(o[hf][2][r] * inv);
      ob[ro + 48] = f2b(o[hf][3][r] * inv);
    }
}

extern "C" void kernel_launch(void* const* d_in, const int* in_sizes, int n_in,
                              void* d_out, int out_size, void* d_ws, size_t ws_size,
                              hipStream_t stream) {
  const float* x  = (const float*)d_in[0];
  const float* Wq = (const float*)d_in[1];
  const float* Wk = (const float*)d_in[2];
  const float* Wv = (const float*)d_in[3];
  const float* Wo = (const float*)d_in[4];
  const int* tok  = (const int*)d_in[5];

  char* ws = (char*)d_ws;
  u16*   xb   = (u16*)(ws);                        // 16 MiB (x bf16; reused as attn-out)
  u16*   wqkv = (u16*)(ws + (16u << 20));          //  6 MiB
  u16*   wo   = (u16*)(ws + (22u << 20));          //  2 MiB
  u16*   qws  = (u16*)(ws + (24u << 20));          // 16 MiB [B][H][S][64]
  u16*   kws  = (u16*)(ws + (40u << 20));          // 16 MiB [B][H][S][64]
  u16*   vws  = (u16*)(ws + (56u << 20));          // 16 MiB [B][H][64][S]
  float2* tab = (float2*)(ws + (72u << 20));       // 512 KiB

  cvt_f32_bf16<<<8192, 256, 0, stream>>>(x, xb, 2097152);
  cvt_f32_bf16<<<1024, 256, 0, stream>>>(Wq, wqkv,               262144);
  cvt_f32_bf16<<<1024, 256, 0, stream>>>(Wk, wqkv + (1u << 20),  262144);
  cvt_f32_bf16<<<1024, 256, 0, stream>>>(Wv, wqkv + (2u << 20),  262144);
  cvt_f32_bf16<<<1024, 256, 0, stream>>>(Wo, wo,                 262144);
  rope_table<<<256, 256, 0, stream>>>(tab);

  gemm_bt<1><<<dim3(64, 24), 256, 0, stream>>>(xb, wqkv, nullptr, 8192, 3072, 1024,
                                               qws, kws, vws);
  rope_apply<<<16384, 256, 0, stream>>>(qws, kws, tab, tok);
  attn_fwd<<<dim3(16, 64), 256, 0, stream>>>(qws, kws, vws, xb);
  gemm_bt<2><<<dim3(64, 8), 256, 0, stream>>>(xb, wo, (float*)d_out, 8192, 1024, 1024,
                                              nullptr, nullptr, nullptr);
}

// Round 3
// 275.301 us; speedup vs baseline: 1.6808x; 1.2369x over previous
//
#include <hip/hip_runtime.h>

typedef unsigned short u16;
typedef unsigned int u32;
typedef unsigned long long u64;
typedef __attribute__((ext_vector_type(8))) short short8;
typedef __attribute__((ext_vector_type(4))) float f32x4;

typedef __attribute__((address_space(3))) void* lds_vp;
typedef const __attribute__((address_space(1))) void* gbl_vp;

#define GLOAD_LDS16(gsrc, ldst) \
  __builtin_amdgcn_global_load_lds((gbl_vp)(gsrc), (lds_vp)(ldst), 16, 0, 0)

#define MFMA_BF16(A, B, C) __builtin_amdgcn_mfma_f32_16x16x32_bf16((A), (B), (C), 0, 0, 0)

__device__ __forceinline__ u16 f2b(float f) {
  u32 u = __builtin_bit_cast(u32, f);
  u += 0x7fffu + ((u >> 16) & 1u);
  return (u16)(u >> 16);
}
__device__ __forceinline__ float b2f(u16 v) {
  return __builtin_bit_cast(float, ((u32)v) << 16);
}
__device__ __forceinline__ u64 pack4(f32x4 v) {
  u32 lo = (u32)f2b(v[0]) | ((u32)f2b(v[1]) << 16);
  u32 hi = (u32)f2b(v[2]) | ((u32)f2b(v[3]) << 16);
  return (u64)lo | ((u64)hi << 32);
}

// ---------------- fp32 -> bf16 conversion (vectorized, G13) ----------------
__global__ void cvt_f32_bf16(const float* __restrict__ in, u16* __restrict__ out, int n4) {
  int i = blockIdx.x * 256 + threadIdx.x;
  if (i >= n4) return;
  float4 v = ((const float4*)in)[i];
  ushort4 o;
  o.x = f2b(v.x); o.y = f2b(v.y); o.z = f2b(v.z); o.w = f2b(v.w);
  ((ushort4*)out)[i] = o;
}

// ---------------- RoPE cos/sin table: [2048 pos][32 pairs] ----------------
__global__ void rope_table(float2* __restrict__ tab) {
  int t = blockIdx.x * 256 + threadIdx.x;      // 65536 threads exactly
  int p = t >> 5, dp = t & 31;
  float inv = (float)pow(10000.0, -(double)dp / 32.0);
  float ang = (float)p * inv;
  tab[t] = make_float2(cosf(ang), sinf(ang));
}

// ---------------- RoPE apply in-place on Q (scaled 0.125) and K ----------------
__global__ void rope_apply(u16* __restrict__ Qd, u16* __restrict__ Kd,
                           const float2* __restrict__ tab, const int* __restrict__ pos) {
  int t = blockIdx.x * 256 + threadIdx.x;      // B*H*S*32 = 4194304 exactly
  int dp = t & 31;
  int s  = (t >> 5) & 2047;
  int bh = t >> 16;
  int p = pos[s];
  float2 cs = tab[(p << 5) + dp];
  size_t base = ((size_t)(bh * 2048 + s)) * 64 + 2 * dp;
  u32 uq = *(const u32*)&Qd[base];
  float x1 = b2f((u16)(uq & 0xffff)), x2 = b2f((u16)(uq >> 16));
  float r1 = (x1 * cs.x - x2 * cs.y) * 0.125f;
  float r2 = (x1 * cs.y + x2 * cs.x) * 0.125f;
  *(u32*)&Qd[base] = (u32)f2b(r1) | ((u32)f2b(r2) << 16);
  u32 uk = *(const u32*)&Kd[base];
  x1 = b2f((u16)(uk & 0xffff)); x2 = b2f((u16)(uk >> 16));
  r1 = x1 * cs.x - x2 * cs.y;
  r2 = x1 * cs.y + x2 * cs.x;
  *(u32*)&Kd[base] = (u32)f2b(r1) | ((u32)f2b(r2) << 16);
}

// ---------------- GEMM C = A @ Bt^T (m97 structure, unchanged this round) ----
template<int EPI>
__global__ __launch_bounds__(256, 2) void gemm_bt(
    const u16* __restrict__ A, const u16* __restrict__ Bt,
    float* __restrict__ Cf, int M, int N, int K,
    u16* __restrict__ qp, u16* __restrict__ kp, u16* __restrict__ vp)
{
  __shared__ u16 As[128 * 32];
  __shared__ u16 Bs[128 * 32];
  const int t = threadIdx.x;
  const int l = t & 63, w = t >> 6;
  const int wr = w >> 1, wc = w & 1;
  const int tm = blockIdx.x * 128, tn = blockIdx.y * 128;
  const int srow = w * 16 + (l >> 2);
  const int scol = (l & 3) * 8;
  const u16* aS = A + (size_t)(tm + srow) * K + scol;
  const u16* bS = Bt + (size_t)(tn + srow) * K + scol;
  f32x4 acc[4][4] = {};
  for (int kt = 0; kt < K; kt += 32) {
    __syncthreads();
    GLOAD_LDS16(aS + kt,              &As[(w * 16) * 32]);
    GLOAD_LDS16(aS + 64 * (size_t)K + kt, &As[(64 + w * 16) * 32]);
    GLOAD_LDS16(bS + kt,              &Bs[(w * 16) * 32]);
    GLOAD_LDS16(bS + 64 * (size_t)K + kt, &Bs[(64 + w * 16) * 32]);
    asm volatile("s_waitcnt vmcnt(0)" ::: "memory");
    __syncthreads();
    short8 af[4], bf[4];
    #pragma unroll
    for (int m = 0; m < 4; ++m)
      af[m] = *(const short8*)&As[(wr * 64 + m * 16 + (l & 15)) * 32 + (l >> 4) * 8];
    #pragma unroll
    for (int n = 0; n < 4; ++n)
      bf[n] = *(const short8*)&Bs[(wc * 64 + n * 16 + (l & 15)) * 32 + (l >> 4) * 8];
    #pragma unroll
    for (int m = 0; m < 4; ++m)
      #pragma unroll
      for (int n = 0; n < 4; ++n)
        acc[m][n] = MFMA_BF16(af[m], bf[n], acc[m][n]);
  }
  const int rl = (l >> 4) * 4;
  const int cl = l & 15;
  if constexpr (EPI == 2) {
    #pragma unroll
    for (int m = 0; m < 4; ++m)
      #pragma unroll
      for (int n = 0; n < 4; ++n) {
        int col = tn + wc * 64 + n * 16 + cl;
        #pragma unroll
        for (int r = 0; r < 4; ++r) {
          int row = tm + wr * 64 + m * 16 + rl + r;
          Cf[(size_t)row * N + col] = acc[m][n][r];
        }
      }
  } else {
    #pragma unroll
    for (int m = 0; m < 4; ++m)
      #pragma unroll
      for (int n = 0; n < 4; ++n) {
        int j0 = tn + wc * 64 + n * 16;
        int which = j0 >> 10;
        int h = (j0 & 1023) >> 6;
        int d = (j0 & 63) + cl;
        u16* dst = which == 0 ? qp : (which == 1 ? kp : vp);
        #pragma unroll
        for (int r = 0; r < 4; ++r) {
          int i = tm + wr * 64 + m * 16 + rl + r;
          int b = i >> 11, s = i & 2047;
          u16 bv = f2b(acc[m][n][r]);
          if (which < 2)
            dst[(size_t)((b * 16 + h) * 2048 + s) * 64 + d] = bv;       // [B][H][S][64]
          else
            dst[(size_t)((b * 16 + h) * 64 + d) * 2048 + s] = bv;       // V^T: [B][H][64][S]
        }
      }
  }
}

// ---------------- causal flash attention, v3: swapped-operand ----------------
// grid (16, B*H); 4 waves; wave = 32 q-rows; KV step 64; dbuf K/V, T2 swizzle.
// Both MFMAs swapped (A<->B): S^T = mfma(K,Q) puts each q-row's 16 keys
// IN-LANE (lane&15 = q) -> row reduce = in-lane VALU + 2 shfl_xor.
// PV swapped too: O^T = mfma(V,P) keeps col = q = lane&15, so m/l/alpha are
// lane-local. LDS read patterns identical to v2 (A/B frags read the same way).
__global__ __launch_bounds__(256, 2) void attn_fwd(
    const u16* __restrict__ Q, const u16* __restrict__ Kg,
    const u16* __restrict__ Vt, u16* __restrict__ Ob)
{
  __shared__ u16 Ks[2][64 * 64];    // [key][d], swizzled
  __shared__ u16 Vs[2][64 * 64];    // [d][key], swizzled
  __shared__ u16 Ps[4][32 * 64];    // per-wave P [q][key], swizzled
  const int t = threadIdx.x;
  const int l = t & 63, w = t >> 6;
  const int bh = blockIdx.y, b = bh >> 4, h = bh & 15;
  const int qb = ((int)gridDim.x - 1 - (int)blockIdx.x) * 128;  // long blocks first
  const int qw = qb + w * 32;
  const int cl = l & 15, ko = l >> 4;

  short8 qf[2][2];                  // B-frag: lane&15 = q, elems = d
  {
    const u16* Qb = Q + (size_t)bh * 2048 * 64;
    #pragma unroll
    for (int hf = 0; hf < 2; ++hf) {
      const u16* qr = Qb + (size_t)(qw + hf * 16 + cl) * 64 + ko * 8;
      qf[hf][0] = *(const short8*)qr;
      qf[hf][1] = *(const short8*)(qr + 32);
    }
  }
  const u16* Kb = Kg + (size_t)bh * 2048 * 64;
  const u16* Vb = Vt + (size_t)bh * 64 * 2048;
  f32x4 o[2][4] = {};               // O^T: col=q=lane&15, reg r -> d = db*16+ko*4+r
  float mrun[2] = {-1e30f, -1e30f};
  float lrun[2] = {0.f, 0.f};

  const int srow = l >> 3;
  const int scb  = l & 7;
  const int nt = (qb >> 6) + 2;

  auto stage = [&](int bf, int kt_) {
    const int kv_ = kt_ * 64;
    #pragma unroll
    for (int i_ = 0; i_ < 2; ++i_) {
      int r0 = w * 16 + i_ * 8;
      int row = r0 + srow;
      int gc = (scb ^ (row & 7)) * 8;           // inverse-swizzled source col (u16)
      GLOAD_LDS16(Kb + (size_t)(kv_ + row) * 64 + gc, &Ks[bf][r0 * 64]);
      GLOAD_LDS16(Vb + (size_t)row * 2048 + kv_ + gc, &Vs[bf][r0 * 64]);
    }
  };

  stage(0, 0);
  for (int kt = 0; kt < nt; ++kt) {
    const int bf = kt & 1;
    const int kv = kt * 64;
    if (kt + 1 < nt) {
      stage(bf ^ 1, kt + 1);
      asm volatile("s_waitcnt vmcnt(4)" ::: "memory");   // tile kt landed; kt+1 in flight
    } else {
      asm volatile("s_waitcnt vmcnt(0)" ::: "memory");
    }
    __builtin_amdgcn_s_barrier();
    if (kv <= qw + 31) {                 // wave-uniform causal gate (=> kv <= qw)
      // ---- QK^T (swapped): s[hf][kbk] = K-tile x Q -> S^T ----
      f32x4 s[2][4] = {};
      #pragma unroll
      for (int kbk = 0; kbk < 4; ++kbk) {
        int row = kbk * 16 + cl, sw = row & 7;          // row = key (A-frag)
        short8 k0 = *(const short8*)&Ks[bf][row * 64 + ((ko ^ sw) << 3)];
        short8 k1 = *(const short8*)&Ks[bf][row * 64 + (((4 + ko) ^ sw) << 3)];
        #pragma unroll
        for (int hf = 0; hf < 2; ++hf) {
          s[hf][kbk] = MFMA_BF16(k0, qf[hf][0], s[hf][kbk]);
          s[hf][kbk] = MFMA_BF16(k1, qf[hf][1], s[hf][kbk]);
        }
      }
      // s[hf][kbk][r]: q = qw+hf*16+cl, key = kv+kbk*16+ko*4+r (all in-lane per q)
      if (kv + 63 > qw) {                // tile touches the diagonal
        #pragma unroll
        for (int hf = 0; hf < 2; ++hf) {
          int q = qw + hf * 16 + cl;
          #pragma unroll
          for (int kbk = 0; kbk < 4; ++kbk) {
            int key0 = kv + kbk * 16 + ko * 4;
            #pragma unroll
            for (int r = 0; r < 4; ++r)
              if (key0 + r > q) s[hf][kbk][r] = -1e30f;
          }
        }
      }
      // ---- online softmax: in-lane over 16 keys + 2 shuffles ----
      #pragma unroll
      for (int hf = 0; hf < 2; ++hf) {
        f32x4 vm;
        #pragma unroll
        for (int j = 0; j < 4; ++j)
          vm[j] = fmaxf(fmaxf(s[hf][0][j], s[hf][1][j]),
                        fmaxf(s[hf][2][j], s[hf][3][j]));
        float tmax = fmaxf(fmaxf(vm[0], vm[1]), fmaxf(vm[2], vm[3]));
        tmax = fmaxf(tmax, __shfl_xor(tmax, 16));
        tmax = fmaxf(tmax, __shfl_xor(tmax, 32));
        // T13 defer-max: skip rescale while tile max stays within THR=8
        if (!__all(tmax - mrun[hf] <= 8.0f)) {
          float mnew = fmaxf(mrun[hf], tmax);
          float al = __expf(mrun[hf] - mnew);
          mrun[hf] = mnew;
          lrun[hf] *= al;
          #pragma unroll
          for (int db = 0; db < 4; ++db) {
            o[hf][db][0] *= al; o[hf][db][1] *= al;
            o[hf][db][2] *= al; o[hf][db][3] *= al;
          }
        }
        f32x4 p[4];
        #pragma unroll
        for (int kbk = 0; kbk < 4; ++kbk)
          #pragma unroll
          for (int j = 0; j < 4; ++j)
            p[kbk][j] = __expf(s[hf][kbk][j] - mrun[hf]);
        f32x4 vs_;
        #pragma unroll
        for (int j = 0; j < 4; ++j)
          vs_[j] = (p[0][j] + p[1][j]) + (p[2][j] + p[3][j]);
        float ts = (vs_[0] + vs_[1]) + (vs_[2] + vs_[3]);
        ts += __shfl_xor(ts, 16);
        ts += __shfl_xor(ts, 32);
        lrun[hf] += ts;
        // write P[q][key] (swizzled), 4 contiguous keys per packed b64 store
        int prow = hf * 16 + cl, sw = prow & 7;
        #pragma unroll
        for (int kbk = 0; kbk < 4; ++kbk) {
          int key0 = kbk * 16 + ko * 4;
          int cb = key0 >> 3, ci = key0 & 7;
          *(u64*)&Ps[w][prow * 64 + ((cb ^ sw) << 3) + ci] = pack4(p[kbk]);
        }
      }
      // cross-lane LDS RAW fence (outside C memory model) + rule-18 sched fence
      asm volatile("s_waitcnt lgkmcnt(0)" ::: "memory");
      __builtin_amdgcn_sched_barrier(0);
      // ---- PV (swapped): o[hf][db] += V^T-tile x P -> O^T ----
      short8 pa[2][2];
      #pragma unroll
      for (int hf = 0; hf < 2; ++hf) {
        int row = hf * 16 + cl, sw = row & 7;
        pa[hf][0] = *(const short8*)&Ps[w][row * 64 + ((ko ^ sw) << 3)];
        pa[hf][1] = *(const short8*)&Ps[w][row * 64 + (((4 + ko) ^ sw) << 3)];
      }
      #pragma unroll
      for (int db = 0; db < 4; ++db) {
        int row = db * 16 + cl, sw = row & 7;           // row = d (A-frag)
        short8 vf0 = *(const short8*)&Vs[bf][row * 64 + ((ko ^ sw) << 3)];
        short8 vf1 = *(const short8*)&Vs[bf][row * 64 + (((4 + ko) ^ sw) << 3)];
        #pragma unroll
        for (int hf = 0; hf < 2; ++hf) {
          o[hf][db] = MFMA_BF16(vf0, pa[hf][0], o[hf][db]);
          o[hf][db] = MFMA_BF16(vf1, pa[hf][1], o[hf][db]);
        }
      }
    }
    asm volatile("" ::: "memory");       // keep LDS reads on this side of the barrier
    __builtin_amdgcn_s_barrier();        // reads done before next stage overwrites
  }
  // ---- epilogue: lane owns q = qw+hf*16+cl; d = db*16+ko*4+r ----
  #pragma unroll
  for (int hf = 0; hf < 2; ++hf) {
    float inv = 1.0f / lrun[hf];
    u16* ob = Ob + (size_t)(b * 2048 + qw + hf * 16 + cl) * 1024 + h * 64 + ko * 4;
    #pragma unroll
    for (int db = 0; db < 4; ++db) {
      f32x4 ov;
      #pragma unroll
      for (int j = 0; j < 4; ++j) ov[j] = o[hf][db][j] * inv;
      *(u64*)&ob[db * 16] = pack4(ov);
    }
  }
}

extern "C" void kernel_launch(void* const* d_in, const int* in_sizes, int n_in,
                              void* d_out, int out_size, void* d_ws, size_t ws_size,
                              hipStream_t stream) {
  const float* x  = (const float*)d_in[0];
  const float* Wq = (const float*)d_in[1];
  const float* Wk = (const float*)d_in[2];
  const float* Wv = (const float*)d_in[3];
  const float* Wo = (const float*)d_in[4];
  const int* tok  = (const int*)d_in[5];

  char* ws = (char*)d_ws;
  u16*   xb   = (u16*)(ws);                        // 16 MiB (x bf16; reused as attn-out)
  u16*   wqkv = (u16*)(ws + (16u << 20));          //  6 MiB
  u16*   wo   = (u16*)(ws + (22u << 20));          //  2 MiB
  u16*   qws  = (u16*)(ws + (24u << 20));          // 16 MiB [B][H][S][64]
  u16*   kws  = (u16*)(ws + (40u << 20));          // 16 MiB [B][H][S][64]
  u16*   vws  = (u16*)(ws + (56u << 20));          // 16 MiB [B][H][64][S]
  float2* tab = (float2*)(ws + (72u << 20));       // 512 KiB

  cvt_f32_bf16<<<8192, 256, 0, stream>>>(x, xb, 2097152);
  cvt_f32_bf16<<<1024, 256, 0, stream>>>(Wq, wqkv,               262144);
  cvt_f32_bf16<<<1024, 256, 0, stream>>>(Wk, wqkv + (1u << 20),  262144);
  cvt_f32_bf16<<<1024, 256, 0, stream>>>(Wv, wqkv + (2u << 20),  262144);
  cvt_f32_bf16<<<1024, 256, 0, stream>>>(Wo, wo,                 262144);
  rope_table<<<256, 256, 0, stream>>>(tab);

  gemm_bt<1><<<dim3(64, 24), 256, 0, stream>>>(xb, wqkv, nullptr, 8192, 3072, 1024,
                                               qws, kws, vws);
  rope_apply<<<16384, 256, 0, stream>>>(qws, kws, tab, tok);
  attn_fwd<<<dim3(16, 64), 256, 0, stream>>>(qws, kws, vws, xb);
  gemm_bt<2><<<dim3(64, 8), 256, 0, stream>>>(xb, wo, (float*)d_out, 8192, 1024, 1024,
                                              nullptr, nullptr, nullptr);
}

// Round 4
// 272.027 us; speedup vs baseline: 1.7011x; 1.0120x over previous
//
#include <hip/hip_runtime.h>

typedef unsigned short u16;
typedef unsigned int u32;
typedef unsigned long long u64;
typedef __attribute__((ext_vector_type(8))) short short8;
typedef __attribute__((ext_vector_type(4))) float f32x4;

typedef __attribute__((address_space(3))) void* lds_vp;
typedef const __attribute__((address_space(1))) void* gbl_vp;

#define GLOAD_LDS16(gsrc, ldst) \
  __builtin_amdgcn_global_load_lds((gbl_vp)(gsrc), (lds_vp)(ldst), 16, 0, 0)

#define MFMA_BF16(A, B, C) __builtin_amdgcn_mfma_f32_16x16x32_bf16((A), (B), (C), 0, 0, 0)

__device__ __forceinline__ u16 f2b(float f) {
  u32 u = __builtin_bit_cast(u32, f);
  u += 0x7fffu + ((u >> 16) & 1u);
  return (u16)(u >> 16);
}
__device__ __forceinline__ float b2f(u16 v) {
  return __builtin_bit_cast(float, ((u32)v) << 16);
}
__device__ __forceinline__ u32 cvtpk(float a, float b) {   // lo=bf16(a), hi=bf16(b)
  u32 r;
  asm("v_cvt_pk_bf16_f32 %0, %1, %2" : "=v"(r) : "v"(a), "v"(b));
  return r;
}
__device__ __forceinline__ u64 pack4(f32x4 v) {
  u32 lo = (u32)f2b(v[0]) | ((u32)f2b(v[1]) << 16);
  u32 hi = (u32)f2b(v[2]) | ((u32)f2b(v[3]) << 16);
  return (u64)lo | ((u64)hi << 32);
}

// ---------------- fp32 -> bf16 conversion (vectorized, G13) ----------------
__global__ void cvt_f32_bf16(const float* __restrict__ in, u16* __restrict__ out, int n4) {
  int i = blockIdx.x * 256 + threadIdx.x;
  if (i >= n4) return;
  float4 v = ((const float4*)in)[i];
  ushort4 o;
  o.x = f2b(v.x); o.y = f2b(v.y); o.z = f2b(v.z); o.w = f2b(v.w);
  ((ushort4*)out)[i] = o;
}

// ---------------- RoPE cos/sin table: [2048 pos][32 pairs] ----------------
__global__ void rope_table(float2* __restrict__ tab) {
  int t = blockIdx.x * 256 + threadIdx.x;      // 65536 threads exactly
  int p = t >> 5, dp = t & 31;
  float inv = (float)pow(10000.0, -(double)dp / 32.0);
  float ang = (float)p * inv;
  tab[t] = make_float2(cosf(ang), sinf(ang));
}

// ---------------- RoPE apply in-place on Q (scaled) and K ----------------
// Q gets 0.125 * log2(e) so attention scores land in log2 domain.
#define QSCALE (0.125f * 1.4426950408889634f)
__global__ void rope_apply(u16* __restrict__ Qd, u16* __restrict__ Kd,
                           const float2* __restrict__ tab, const int* __restrict__ pos) {
  int t = blockIdx.x * 256 + threadIdx.x;      // B*H*S*32 = 4194304 exactly
  int dp = t & 31;
  int s  = (t >> 5) & 2047;
  int bh = t >> 16;
  int p = pos[s];
  float2 cs = tab[(p << 5) + dp];
  size_t base = ((size_t)(bh * 2048 + s)) * 64 + 2 * dp;
  u32 uq = *(const u32*)&Qd[base];
  float x1 = b2f((u16)(uq & 0xffff)), x2 = b2f((u16)(uq >> 16));
  float r1 = (x1 * cs.x - x2 * cs.y) * QSCALE;
  float r2 = (x1 * cs.y + x2 * cs.x) * QSCALE;
  *(u32*)&Qd[base] = (u32)f2b(r1) | ((u32)f2b(r2) << 16);
  u32 uk = *(const u32*)&Kd[base];
  x1 = b2f((u16)(uk & 0xffff)); x2 = b2f((u16)(uk >> 16));
  r1 = x1 * cs.x - x2 * cs.y;
  r2 = x1 * cs.y + x2 * cs.x;
  *(u32*)&Kd[base] = (u32)f2b(r1) | ((u32)f2b(r2) << 16);
}

// ---------------- GEMM C = A @ Bt^T (m97 structure, unchanged this round) ----
template<int EPI>
__global__ __launch_bounds__(256, 2) void gemm_bt(
    const u16* __restrict__ A, const u16* __restrict__ Bt,
    float* __restrict__ Cf, int M, int N, int K,
    u16* __restrict__ qp, u16* __restrict__ kp, u16* __restrict__ vp)
{
  __shared__ u16 As[128 * 32];
  __shared__ u16 Bs[128 * 32];
  const int t = threadIdx.x;
  const int l = t & 63, w = t >> 6;
  const int wr = w >> 1, wc = w & 1;
  const int tm = blockIdx.x * 128, tn = blockIdx.y * 128;
  const int srow = w * 16 + (l >> 2);
  const int scol = (l & 3) * 8;
  const u16* aS = A + (size_t)(tm + srow) * K + scol;
  const u16* bS = Bt + (size_t)(tn + srow) * K + scol;
  f32x4 acc[4][4] = {};
  for (int kt = 0; kt < K; kt += 32) {
    __syncthreads();
    GLOAD_LDS16(aS + kt,              &As[(w * 16) * 32]);
    GLOAD_LDS16(aS + 64 * (size_t)K + kt, &As[(64 + w * 16) * 32]);
    GLOAD_LDS16(bS + kt,              &Bs[(w * 16) * 32]);
    GLOAD_LDS16(bS + 64 * (size_t)K + kt, &Bs[(64 + w * 16) * 32]);
    asm volatile("s_waitcnt vmcnt(0)" ::: "memory");
    __syncthreads();
    short8 af[4], bf[4];
    #pragma unroll
    for (int m = 0; m < 4; ++m)
      af[m] = *(const short8*)&As[(wr * 64 + m * 16 + (l & 15)) * 32 + (l >> 4) * 8];
    #pragma unroll
    for (int n = 0; n < 4; ++n)
      bf[n] = *(const short8*)&Bs[(wc * 64 + n * 16 + (l & 15)) * 32 + (l >> 4) * 8];
    #pragma unroll
    for (int m = 0; m < 4; ++m)
      #pragma unroll
      for (int n = 0; n < 4; ++n)
        acc[m][n] = MFMA_BF16(af[m], bf[n], acc[m][n]);
  }
  const int rl = (l >> 4) * 4;
  const int cl = l & 15;
  if constexpr (EPI == 2) {
    #pragma unroll
    for (int m = 0; m < 4; ++m)
      #pragma unroll
      for (int n = 0; n < 4; ++n) {
        int col = tn + wc * 64 + n * 16 + cl;
        #pragma unroll
        for (int r = 0; r < 4; ++r) {
          int row = tm + wr * 64 + m * 16 + rl + r;
          Cf[(size_t)row * N + col] = acc[m][n][r];
        }
      }
  } else {
    #pragma unroll
    for (int m = 0; m < 4; ++m)
      #pragma unroll
      for (int n = 0; n < 4; ++n) {
        int j0 = tn + wc * 64 + n * 16;
        int which = j0 >> 10;
        int h = (j0 & 1023) >> 6;
        int d = (j0 & 63) + cl;
        u16* dst = which == 0 ? qp : (which == 1 ? kp : vp);
        #pragma unroll
        for (int r = 0; r < 4; ++r) {
          int i = tm + wr * 64 + m * 16 + rl + r;
          int b = i >> 11, s = i & 2047;
          u16 bv = f2b(acc[m][n][r]);
          if (which < 2)
            dst[(size_t)((b * 16 + h) * 2048 + s) * 64 + d] = bv;       // [B][H][S][64]
          else
            dst[(size_t)((b * 16 + h) * 64 + d) * 2048 + s] = bv;       // V^T: [B][H][64][S]
        }
      }
  }
}

// ---------------- causal flash attention, v4 ----------------
// v3 + : unroll-2 (compile-time dbuf index -> hoisted swizzled addrs),
// cvt_pk P-packing, log2-domain softmax (exp2, Q pre-scaled by log2e),
// deferred l-reduction (epilogue-only shuffles), V-frags hoisted before
// softmax, setprio around MFMA clusters (T5).
__global__ __launch_bounds__(256, 3) void attn_fwd(
    const u16* __restrict__ Q, const u16* __restrict__ Kg,
    const u16* __restrict__ Vt, u16* __restrict__ Ob)
{
  __shared__ u16 Ks[2][64 * 64];    // [key][d], swizzled
  __shared__ u16 Vs[2][64 * 64];    // [d][key], swizzled
  __shared__ u16 Ps[4][32 * 64];    // per-wave P [q][key], swizzled
  const int t = threadIdx.x;
  const int l = t & 63, w = t >> 6;
  const int bh = blockIdx.y, b = bh >> 4, h = bh & 15;
  const int qb = ((int)gridDim.x - 1 - (int)blockIdx.x) * 128;  // long blocks first
  const int qw = qb + w * 32;
  const int cl = l & 15, ko = l >> 4;

  short8 qf[2][2];                  // B-frag: lane&15 = q, elems = d
  {
    const u16* Qb = Q + (size_t)bh * 2048 * 64;
    #pragma unroll
    for (int hf = 0; hf < 2; ++hf) {
      const u16* qr = Qb + (size_t)(qw + hf * 16 + cl) * 64 + ko * 8;
      qf[hf][0] = *(const short8*)qr;
      qf[hf][1] = *(const short8*)(qr + 32);
    }
  }
  const u16* Kb = Kg + (size_t)bh * 2048 * 64;
  const u16* Vb = Vt + (size_t)bh * 64 * 2048;
  f32x4 o[2][4] = {};               // O^T: col=q=lane&15, reg r -> d = db*16+ko*4+r
  float mrun[2] = {-1e30f, -1e30f};   // log2 domain
  float lpart[2] = {0.f, 0.f};        // per-lane partial sum (reduced at epilogue)

  const int srow = l >> 3;
  const int scb  = l & 7;
  const int nt = (qb >> 6) + 2;     // always even

  auto stage = [&](int bf, int kt_) {
    const int kv_ = kt_ * 64;
    #pragma unroll
    for (int i_ = 0; i_ < 2; ++i_) {
      int r0 = w * 16 + i_ * 8;
      int row = r0 + srow;
      int gc = (scb ^ (row & 7)) * 8;           // inverse-swizzled source col (u16)
      GLOAD_LDS16(Kb + (size_t)(kv_ + row) * 64 + gc, &Ks[bf][r0 * 64]);
      GLOAD_LDS16(Vb + (size_t)row * 2048 + kv_ + gc, &Vs[bf][r0 * 64]);
    }
  };

  auto step = [&](int kt, int bf) {             // bf is a literal at both call sites
    const int kv = kt * 64;
    if (kt + 1 < nt) {
      stage(bf ^ 1, kt + 1);
      asm volatile("s_waitcnt vmcnt(4)" ::: "memory");   // tile kt landed; kt+1 in flight
    } else {
      asm volatile("s_waitcnt vmcnt(0)" ::: "memory");
    }
    __builtin_amdgcn_s_barrier();
    if (kv <= qw + 31) {                 // wave-uniform causal gate (=> kv <= qw)
      // ---- QK^T (swapped): s[hf][kbk] = K-tile x Q -> S^T ----
      f32x4 s[2][4] = {};
      __builtin_amdgcn_s_setprio(1);
      #pragma unroll
      for (int kbk = 0; kbk < 4; ++kbk) {
        int row = kbk * 16 + cl, sw = row & 7;          // row = key (A-frag)
        short8 k0 = *(const short8*)&Ks[bf][row * 64 + ((ko ^ sw) << 3)];
        short8 k1 = *(const short8*)&Ks[bf][row * 64 + (((4 + ko) ^ sw) << 3)];
        #pragma unroll
        for (int hf = 0; hf < 2; ++hf) {
          s[hf][kbk] = MFMA_BF16(k0, qf[hf][0], s[hf][kbk]);
          s[hf][kbk] = MFMA_BF16(k1, qf[hf][1], s[hf][kbk]);
        }
      }
      __builtin_amdgcn_s_setprio(0);
      // V-fragments hoisted: 8 independent ds_reads overlap the softmax VALU
      short8 vf[4][2];
      #pragma unroll
      for (int db = 0; db < 4; ++db) {
        int row = db * 16 + cl, sw = row & 7;           // row = d (A-frag)
        vf[db][0] = *(const short8*)&Vs[bf][row * 64 + ((ko ^ sw) << 3)];
        vf[db][1] = *(const short8*)&Vs[bf][row * 64 + (((4 + ko) ^ sw) << 3)];
      }
      // s[hf][kbk][r]: q = qw+hf*16+cl, key = kv+kbk*16+ko*4+r (in-lane per q)
      if (kv + 63 > qw) {                // tile touches the diagonal
        #pragma unroll
        for (int hf = 0; hf < 2; ++hf) {
          int q = qw + hf * 16 + cl;
          #pragma unroll
          for (int kbk = 0; kbk < 4; ++kbk) {
            int key0 = kv + kbk * 16 + ko * 4;
            #pragma unroll
            for (int r = 0; r < 4; ++r)
              if (key0 + r > q) s[hf][kbk][r] = -1e30f;
          }
        }
      }
      // ---- online softmax (log2 domain) ----
      #pragma unroll
      for (int hf = 0; hf < 2; ++hf) {
        f32x4 vm;
        #pragma unroll
        for (int j = 0; j < 4; ++j)
          vm[j] = fmaxf(fmaxf(s[hf][0][j], s[hf][1][j]),
                        fmaxf(s[hf][2][j], s[hf][3][j]));
        float tmax = fmaxf(fmaxf(vm[0], vm[1]), fmaxf(vm[2], vm[3]));
        tmax = fmaxf(tmax, __shfl_xor(tmax, 16));
        tmax = fmaxf(tmax, __shfl_xor(tmax, 32));
        // T13 defer-max, THR = 8 nats = 11.5416 in log2 units
        if (!__all(tmax - mrun[hf] <= 11.5416f)) {
          float mnew = fmaxf(mrun[hf], tmax);
          float al = exp2f(mrun[hf] - mnew);
          mrun[hf] = mnew;
          lpart[hf] *= al;
          #pragma unroll
          for (int db = 0; db < 4; ++db) {
            o[hf][db][0] *= al; o[hf][db][1] *= al;
            o[hf][db][2] *= al; o[hf][db][3] *= al;
          }
        }
        f32x4 p[4];
        #pragma unroll
        for (int kbk = 0; kbk < 4; ++kbk)
          #pragma unroll
          for (int j = 0; j < 4; ++j)
            p[kbk][j] = exp2f(s[hf][kbk][j] - mrun[hf]);
        // per-lane partial sum only (cross-lane reduce deferred to epilogue)
        f32x4 vs_;
        #pragma unroll
        for (int j = 0; j < 4; ++j)
          vs_[j] = (p[0][j] + p[1][j]) + (p[2][j] + p[3][j]);
        lpart[hf] += (vs_[0] + vs_[1]) + (vs_[2] + vs_[3]);
        // write P[q][key] (swizzled), cvt_pk pairs -> one b64 store per kbk
        int prow = hf * 16 + cl, sw = prow & 7;
        #pragma unroll
        for (int kbk = 0; kbk < 4; ++kbk) {
          int key0 = kbk * 16 + ko * 4;
          int cb = key0 >> 3, ci = key0 & 7;
          u32 c0 = cvtpk(p[kbk][0], p[kbk][1]);
          u32 c1 = cvtpk(p[kbk][2], p[kbk][3]);
          *(u64*)&Ps[w][prow * 64 + ((cb ^ sw) << 3) + ci] = (u64)c0 | ((u64)c1 << 32);
        }
      }
      // cross-lane LDS RAW fence (outside C memory model) + rule-18 sched fence
      asm volatile("s_waitcnt lgkmcnt(0)" ::: "memory");
      __builtin_amdgcn_sched_barrier(0);
      // ---- PV (swapped): o[hf][db] += V^T-tile x P -> O^T ----
      short8 pa[2][2];
      #pragma unroll
      for (int hf = 0; hf < 2; ++hf) {
        int row = hf * 16 + cl, sw = row & 7;
        pa[hf][0] = *(const short8*)&Ps[w][row * 64 + ((ko ^ sw) << 3)];
        pa[hf][1] = *(const short8*)&Ps[w][row * 64 + (((4 + ko) ^ sw) << 3)];
      }
      __builtin_amdgcn_s_setprio(1);
      #pragma unroll
      for (int db = 0; db < 4; ++db)
        #pragma unroll
        for (int hf = 0; hf < 2; ++hf) {
          o[hf][db] = MFMA_BF16(vf[db][0], pa[hf][0], o[hf][db]);
          o[hf][db] = MFMA_BF16(vf[db][1], pa[hf][1], o[hf][db]);
        }
      __builtin_amdgcn_s_setprio(0);
    }
    asm volatile("" ::: "memory");       // keep LDS reads on this side of the barrier
    __builtin_amdgcn_s_barrier();        // reads done before next stage overwrites
  };

  stage(0, 0);
  for (int kt = 0; kt < nt; kt += 2) {   // nt even; bf literal per call site
    step(kt, 0);
    step(kt + 1, 1);
  }
  // ---- epilogue: lane owns q = qw+hf*16+cl; d = db*16+ko*4+r ----
  #pragma unroll
  for (int hf = 0; hf < 2; ++hf) {
    float ts = lpart[hf];
    ts += __shfl_xor(ts, 16);
    ts += __shfl_xor(ts, 32);
    float inv = 1.0f / ts;
    u16* ob = Ob + (size_t)(b * 2048 + qw + hf * 16 + cl) * 1024 + h * 64 + ko * 4;
    #pragma unroll
    for (int db = 0; db < 4; ++db) {
      f32x4 ov;
      #pragma unroll
      for (int j = 0; j < 4; ++j) ov[j] = o[hf][db][j] * inv;
      *(u64*)&ob[db * 16] = pack4(ov);
    }
  }
}

extern "C" void kernel_launch(void* const* d_in, const int* in_sizes, int n_in,
                              void* d_out, int out_size, void* d_ws, size_t ws_size,
                              hipStream_t stream) {
  const float* x  = (const float*)d_in[0];
  const float* Wq = (const float*)d_in[1];
  const float* Wk = (const float*)d_in[2];
  const float* Wv = (const float*)d_in[3];
  const float* Wo = (const float*)d_in[4];
  const int* tok  = (const int*)d_in[5];

  char* ws = (char*)d_ws;
  u16*   xb   = (u16*)(ws);                        // 16 MiB (x bf16; reused as attn-out)
  u16*   wqkv = (u16*)(ws + (16u << 20));          //  6 MiB
  u16*   wo   = (u16*)(ws + (22u << 20));          //  2 MiB
  u16*   qws  = (u16*)(ws + (24u << 20));          // 16 MiB [B][H][S][64]
  u16*   kws  = (u16*)(ws + (40u << 20));          // 16 MiB [B][H][S][64]
  u16*   vws  = (u16*)(ws + (56u << 20));          // 16 MiB [B][H][64][S]
  float2* tab = (float2*)(ws + (72u << 20));       // 512 KiB

  cvt_f32_bf16<<<8192, 256, 0, stream>>>(x, xb, 2097152);
  cvt_f32_bf16<<<1024, 256, 0, stream>>>(Wq, wqkv,               262144);
  cvt_f32_bf16<<<1024, 256, 0, stream>>>(Wk, wqkv + (1u << 20),  262144);
  cvt_f32_bf16<<<1024, 256, 0, stream>>>(Wv, wqkv + (2u << 20),  262144);
  cvt_f32_bf16<<<1024, 256, 0, stream>>>(Wo, wo,                 262144);
  rope_table<<<256, 256, 0, stream>>>(tab);

  gemm_bt<1><<<dim3(64, 24), 256, 0, stream>>>(xb, wqkv, nullptr, 8192, 3072, 1024,
                                               qws, kws, vws);
  rope_apply<<<16384, 256, 0, stream>>>(qws, kws, tab, tok);
  attn_fwd<<<dim3(16, 64), 256, 0, stream>>>(qws, kws, vws, xb);
  gemm_bt<2><<<dim3(64, 8), 256, 0, stream>>>(xb, wo, (float*)d_out, 8192, 1024, 1024,
                                              nullptr, nullptr, nullptr);
}